// Round 1
// baseline (232.989 us; speedup 1.0000x reference)
//
#include <hip/hip_runtime.h>
#include <math.h>

#define DIM 128
#define LN_EPS 1e-5f
#define CAP 64          // max in-degree capacity (Poisson(16): P(>64) ~ 1e-21)

typedef unsigned short bf16_t;
typedef unsigned short u16;
typedef __attribute__((ext_vector_type(8))) short bf16x8;
typedef __attribute__((ext_vector_type(4))) float f32x4;

__device__ __forceinline__ bf16_t f2bf(float f) {
    unsigned u = __builtin_bit_cast(unsigned, f);
    u += 0x7FFFu + ((u >> 16) & 1u);          // round-to-nearest-even
    return (bf16_t)(u >> 16);
}
__device__ __forceinline__ float bf2f(bf16_t h) {
    unsigned u = ((unsigned)h) << 16;
    return __builtin_bit_cast(float, u);
}

// ---------------------------------------------------------------------------
// Prep kernel: replaces the cursor memset AND builds WT = bf16(W^T) once in
// global memory (32 KB — L1-resident per CU, L2-resident per XCD). This kills
// the per-gemm-block LDS staging (64 scalar ds_write_u16/thread, 16-way bank
// conflicts, 34 KB LDS occupancy cap) that dominated gemm_fill_kernel.
// ---------------------------------------------------------------------------
__global__ __launch_bounds__(256) void prep_kernel(
    const float* __restrict__ W, bf16_t* __restrict__ WT,
    int* __restrict__ cursor, int N)
{
    const int tid = blockIdx.x * 256 + threadIdx.x;
    if (tid < N) cursor[tid] = 0;
    if (tid < (DIM * DIM / 4)) {
        const float4 w = ((const float4*)W)[tid];   // W[k][n0..n0+3], coalesced
        const int k  = tid >> 5;                    // 0..127
        const int n0 = (tid & 31) * 4;
        WT[(n0 + 0) * DIM + k] = f2bf(w.x);
        WT[(n0 + 1) * DIM + k] = f2bf(w.y);
        WT[(n0 + 2) * DIM + k] = f2bf(w.z);
        WT[(n0 + 3) * DIM + k] = f2bf(w.w);
    }
}

// ---------------------------------------------------------------------------
// Fused kernel: blocks [0, FB) do the edge-bucket fill; blocks [FB, FB+GB)
// do m = H @ W via bf16 MFMA, writing M interleaved as [node][batch][dim].
// B-fragments are read DIRECTLY from global WT (bf16x8 = 16 B/lane). WT is
// 32 KB so it lives in L1/L2; no LDS, no __syncthreads, no staging.
// eidxT is TRANSPOSED: eidxT[pos * N + node] (ushort) so fill's writes for
// the hot low-pos slices are dense (64 nodes per 128B line).
// ---------------------------------------------------------------------------
__global__ __launch_bounds__(256) void gemm_fill_kernel(
    const float* __restrict__ Hmat, const bf16_t* __restrict__ WT,
    bf16_t* __restrict__ Mout,
    const int* __restrict__ src, const int* __restrict__ dst,
    int* __restrict__ cursor, u16* __restrict__ eidxT,
    int nrows, int N, int E, int FB)
{
    if ((int)blockIdx.x < FB) {
        // ---- fill part ----
        int e = blockIdx.x * 256 + threadIdx.x;
        if (e < E) {
            int d = dst[e];
            int pos = atomicAdd(&cursor[d], 1);
            if (pos < CAP) eidxT[(size_t)pos * N + d] = (u16)src[e];
        }
        return;
    }

    // ---- gemm part ----
    const int tid = threadIdx.x;
    const int gblock = blockIdx.x - FB;

    const int wave = tid >> 6;
    const int lane = tid & 63;
    const int quad = lane >> 4;
    const int l15  = lane & 15;

    // A row this lane feeds: A[m=lane&15][k=quad*8+j]
    const int arow = gblock * 64 + wave * 16 + l15;
    const float* Arow = Hmat + (size_t)((arow < nrows) ? arow : 0) * DIM;
    // B base for this lane: WT[n = t*16 + l15][k], row-major [n][k]
    const bf16_t* Bbase = WT + (size_t)l15 * DIM;

    f32x4 acc[8];
    #pragma unroll
    for (int t = 0; t < 8; ++t) acc[t] = (f32x4){0.f, 0.f, 0.f, 0.f};

    #pragma unroll
    for (int ks = 0; ks < 4; ++ks) {
        const int k0 = ks * 32 + quad * 8;
        float4 a0 = *(const float4*)&Arow[k0];
        float4 a1 = *(const float4*)&Arow[k0 + 4];
        bf16x8 af;
        af[0] = (short)f2bf(a0.x); af[1] = (short)f2bf(a0.y);
        af[2] = (short)f2bf(a0.z); af[3] = (short)f2bf(a0.w);
        af[4] = (short)f2bf(a1.x); af[5] = (short)f2bf(a1.y);
        af[6] = (short)f2bf(a1.z); af[7] = (short)f2bf(a1.w);

        #pragma unroll
        for (int t = 0; t < 8; ++t) {
            bf16x8 bf = *(const bf16x8*)&Bbase[t * 16 * DIM + k0];
            acc[t] = __builtin_amdgcn_mfma_f32_16x16x32_bf16(af, bf, acc[t], 0, 0, 0);
        }
    }

    // C/D: col = t*16 + l15, row = quad*4 + reg. Write interleaved [n][b][dim].
    const int outrowbase = gblock * 64 + wave * 16 + quad * 4;
    #pragma unroll
    for (int r = 0; r < 4; ++r) {
        int rr = outrowbase + r;
        if (rr < nrows) {
            int b = (rr >= N) ? 1 : 0;
            int n = rr - (b ? N : 0);
            bf16_t* orow = Mout + ((size_t)n * 2 + b) * DIM + l15;
            #pragma unroll
            for (int t = 0; t < 8; ++t)
                orow[t * 16] = f2bf(acc[t][r]);
        }
    }
}

// ---------------------------------------------------------------------------
// Gather + GELU + residual + LayerNorm.
// One 64-lane wave per dst node: lane -> (b = lane>>5, chunk c4 = lane&31).
// M interleaved: logical (b, s) row at ushort4 index s*64 + b*32 + c4
//                = s*64 + lane  -> 512 contiguous bytes per wave per edge.
// ---------------------------------------------------------------------------
__global__ __launch_bounds__(256) void gather_kernel(
    const bf16_t* __restrict__ M, const float* __restrict__ Hmat,
    const int* __restrict__ cursor, const u16* __restrict__ eidxT,
    const float* __restrict__ gamma, const float* __restrict__ beta,
    float* __restrict__ out, int N)
{
    const int wave = threadIdx.x >> 6;
    const int lane = threadIdx.x & 63;
    const int node = blockIdx.x * 4 + wave;
    if (node >= N) return;

    const int b  = lane >> 5;
    const int c4 = lane & 31;

    int cnt = cursor[node];
    if (cnt > CAP) cnt = CAP;

    // lane l holds the index of edge slot l (transposed bucket read)
    int myidx = (lane < cnt) ? (int)eidxT[(size_t)lane * N + node] : 0;

    const ushort4* M4 = (const ushort4*)M;

    float acc0 = 0.f, acc1 = 0.f, acc2 = 0.f, acc3 = 0.f;
    int j = 0;
    for (; j + 8 <= cnt; j += 8) {
        ushort4 v[8];
        #pragma unroll
        for (int q = 0; q < 8; ++q) {
            int s = __shfl(myidx, j + q, 64);
            v[q] = M4[(size_t)s * 64 + lane];
        }
        #pragma unroll
        for (int q = 0; q < 8; ++q) {
            acc0 += bf2f(v[q].x); acc1 += bf2f(v[q].y);
            acc2 += bf2f(v[q].z); acc3 += bf2f(v[q].w);
        }
    }
    for (; j < cnt; ++j) {
        int s = __shfl(myidx, j, 64);
        ushort4 v0 = M4[(size_t)s * 64 + lane];
        acc0 += bf2f(v0.x); acc1 += bf2f(v0.y);
        acc2 += bf2f(v0.z); acc3 += bf2f(v0.w);
    }

    // x = H + gelu_exact(acc)
    const size_t elembase = ((size_t)b * N + node) * DIM + c4 * 4;
    float4 h = *(const float4*)&Hmat[elembase];
    const float inv_sqrt2 = 0.70710678118654752f;
    float x0 = h.x + 0.5f * acc0 * (1.f + erff(acc0 * inv_sqrt2));
    float x1 = h.y + 0.5f * acc1 * (1.f + erff(acc1 * inv_sqrt2));
    float x2 = h.z + 0.5f * acc2 * (1.f + erff(acc2 * inv_sqrt2));
    float x3 = h.w + 0.5f * acc3 * (1.f + erff(acc3 * inv_sqrt2));

    // LayerNorm over the 32-lane half-wave (128 elems)
    float s  = x0 + x1 + x2 + x3;
    float ss = x0 * x0 + x1 * x1 + x2 * x2 + x3 * x3;
    #pragma unroll
    for (int o = 16; o > 0; o >>= 1) {
        s  += __shfl_xor(s,  o, 64);
        ss += __shfl_xor(ss, o, 64);
    }
    const float mean = s * (1.f / DIM);
    const float var  = ss * (1.f / DIM) - mean * mean;
    const float inv  = rsqrtf(var + LN_EPS);

    float4 gm = *(const float4*)&gamma[c4 * 4];
    float4 bt = *(const float4*)&beta[c4 * 4];
    float4 o;
    o.x = (x0 - mean) * inv * gm.x + bt.x;
    o.y = (x1 - mean) * inv * gm.y + bt.y;
    o.z = (x2 - mean) * inv * gm.z + bt.z;
    o.w = (x3 - mean) * inv * gm.w + bt.w;
    *(float4*)&out[elembase] = o;
}

// ---------------------------------------------------------------------------
extern "C" void kernel_launch(void* const* d_in, const int* in_sizes, int n_in,
                              void* d_out, int out_size, void* d_ws, size_t ws_size,
                              hipStream_t stream)
{
    const float* H     = (const float*)d_in[0];
    const int*   src   = (const int*)  d_in[1];
    const int*   dst   = (const int*)  d_in[2];
    const float* W     = (const float*)d_in[3];
    const float* gamma = (const float*)d_in[4];
    const float* beta  = (const float*)d_in[5];
    float* out = (float*)d_out;

    const int E     = in_sizes[1];
    const int total = in_sizes[0];      // B * N * D
    const int nrows = total / DIM;      // B * N
    const int N     = nrows / 2;        // B = 2 per reference

    // Workspace layout (~32.3 MB)
    char* ws = (char*)d_ws;
    bf16_t* Mbuf = (bf16_t*)ws;   ws += (size_t)total * sizeof(bf16_t);
    int* cursor  = (int*)ws;      ws += (size_t)N * sizeof(int);
    u16* eidxT   = (u16*)ws;      ws += (size_t)CAP * N * sizeof(u16);
    bf16_t* WT   = (bf16_t*)ws;   ws += (size_t)DIM * DIM * sizeof(bf16_t);

    const int FB = (E + 255) / 256;        // fill blocks (first — latency-bound)
    const int GB = (nrows + 63) / 64;      // gemm blocks

    // 0) prep: cursor = 0 (replaces memset) + WT = bf16(W^T)
    int prep_elems = (N > DIM * DIM / 4) ? N : DIM * DIM / 4;
    prep_kernel<<<(prep_elems + 255) / 256, 256, 0, stream>>>(W, WT, cursor, N);

    // 1+2) fused: edge bucketing  ||  m = H @ W (bf16 MFMA, B-frags from global WT)
    gemm_fill_kernel<<<FB + GB, 256, 0, stream>>>(H, WT, Mbuf, src, dst,
                                                  cursor, eidxT, nrows, N, E, FB);

    // 3) fused gather + gelu + residual + layernorm
    gather_kernel<<<(N + 3) / 4, 256, 0, stream>>>(Mbuf, H, cursor, eidxT,
                                                   gamma, beta, out, N);
}

// Round 2
// 232.375 us; speedup vs baseline: 1.0026x; 1.0026x over previous
//
#include <hip/hip_runtime.h>
#include <math.h>

#define DIM 128
#define LN_EPS 1e-5f
#define CAP 64          // max in-degree capacity (Poisson(16): P(>64) ~ 1e-21)
#define TPW 2           // row-tiles (16 H-rows) per wave in gemm_kernel

typedef unsigned short bf16_t;
typedef unsigned short u16;
typedef __attribute__((ext_vector_type(8))) short bf16x8;
typedef __attribute__((ext_vector_type(4))) float f32x4;

__device__ __forceinline__ bf16_t f2bf(float f) {
    unsigned u = __builtin_bit_cast(unsigned, f);
    u += 0x7FFFu + ((u >> 16) & 1u);          // round-to-nearest-even
    return (bf16_t)(u >> 16);
}
__device__ __forceinline__ float bf2f(bf16_t h) {
    unsigned u = ((unsigned)h) << 16;
    return __builtin_bit_cast(float, u);
}

// ---------------------------------------------------------------------------
// Prep: zero cursor (replaces memset) + build WT = bf16(W^T) once in global
// (32 KB). WT[n][k] rows are contiguous -> A-fragment loads are 16B vector.
// ---------------------------------------------------------------------------
__global__ __launch_bounds__(256) void prep_kernel(
    const float* __restrict__ W, bf16_t* __restrict__ WT,
    int* __restrict__ cursor, int N)
{
    const int tid = blockIdx.x * 256 + threadIdx.x;
    if (tid < N) cursor[tid] = 0;
    if (tid < (DIM * DIM / 4)) {
        const float4 w = ((const float4*)W)[tid];   // W[k][n0..n0+3], coalesced
        const int k  = tid >> 5;                    // 0..127
        const int n0 = (tid & 31) * 4;
        WT[(n0 + 0) * DIM + k] = f2bf(w.x);
        WT[(n0 + 1) * DIM + k] = f2bf(w.y);
        WT[(n0 + 2) * DIM + k] = f2bf(w.z);
        WT[(n0 + 3) * DIM + k] = f2bf(w.w);
    }
}

// ---------------------------------------------------------------------------
// Edge bucketing (own kernel: keeps its VGPR footprint at ~50 so it runs at
// full occupancy instead of inheriting the gemm's fat register allocation).
// eidxT is TRANSPOSED: eidxT[pos * N + node].
// ---------------------------------------------------------------------------
__global__ __launch_bounds__(256) void fill_kernel(
    const int* __restrict__ src, const int* __restrict__ dst,
    int* __restrict__ cursor, u16* __restrict__ eidxT, int N, int E)
{
    int e = blockIdx.x * 256 + threadIdx.x;
    if (e < E) {
        int d = dst[e];
        int pos = atomicAdd(&cursor[d], 1);
        if (pos < CAP) eidxT[(size_t)pos * N + d] = (u16)src[e];
    }
}

// ---------------------------------------------------------------------------
// m = H @ W via SWAPPED-operand MFMA: D = WT * H^T = (H W)^T per tile.
//   A <- WT fragments: depend only on (t, ks, lane) -> loaded ONCE per wave
//        into 32 bf16x8 registers (128 VGPRs), reused for every row-tile.
//        No LDS, no barriers, no per-MFMA reload (round-1 flaw fixed).
//   B <- H row fragments: lane reads its OWN H row contiguously (2 x float4).
//   D: col(lane&15) = H-row, row(quad*4+r) = output dim -> each lane holds 4
//        consecutive output dims -> vectorized ushort4 epilogue stores.
// Mout stays interleaved [node][batch][dim] for the gather kernel.
// ---------------------------------------------------------------------------
__global__ __launch_bounds__(256) void gemm_kernel(
    const float* __restrict__ Hmat, const bf16_t* __restrict__ WT,
    bf16_t* __restrict__ Mout, int nrows, int N)
{
    const int tid  = threadIdx.x;
    const int wave = tid >> 6;
    const int lane = tid & 63;
    const int quad = lane >> 4;
    const int l15  = lane & 15;

    // ---- load all W fragments once: wf[t*4+ks] = A-frag of tile t, k-step ks
    bf16x8 wf[32];
    #pragma unroll
    for (int t = 0; t < 8; ++t)
        #pragma unroll
        for (int ks = 0; ks < 4; ++ks)
            wf[t * 4 + ks] = *(const bf16x8*)
                &WT[(size_t)(t * 16 + l15) * DIM + ks * 32 + quad * 8];

    const int baserow = (blockIdx.x * 4 + wave) * (TPW * 16);

    #pragma unroll
    for (int rt = 0; rt < TPW; ++rt) {
        const int arow = baserow + rt * 16 + l15;
        const float* Arow = Hmat + (size_t)((arow < nrows) ? arow : 0) * DIM;

        f32x4 acc[8];
        #pragma unroll
        for (int t = 0; t < 8; ++t) acc[t] = (f32x4){0.f, 0.f, 0.f, 0.f};

        #pragma unroll
        for (int ks = 0; ks < 4; ++ks) {
            const int k0 = ks * 32 + quad * 8;
            float4 a0 = *(const float4*)&Arow[k0];
            float4 a1 = *(const float4*)&Arow[k0 + 4];
            bf16x8 hf;
            hf[0] = (short)f2bf(a0.x); hf[1] = (short)f2bf(a0.y);
            hf[2] = (short)f2bf(a0.z); hf[3] = (short)f2bf(a0.w);
            hf[4] = (short)f2bf(a1.x); hf[5] = (short)f2bf(a1.y);
            hf[6] = (short)f2bf(a1.z); hf[7] = (short)f2bf(a1.w);

            #pragma unroll
            for (int t = 0; t < 8; ++t)
                acc[t] = __builtin_amdgcn_mfma_f32_16x16x32_bf16(
                             wf[t * 4 + ks], hf, acc[t], 0, 0, 0);
        }

        // Epilogue: lane holds M[arow][t*16 + quad*4 + r], r=0..3 consecutive.
        if (arow < nrows) {
            const int b = (arow >= N) ? 1 : 0;
            const int n = arow - (b ? N : 0);
            bf16_t* orow = Mout + ((size_t)n * 2 + b) * DIM;
            #pragma unroll
            for (int t = 0; t < 8; ++t) {
                ushort4 o;
                o.x = f2bf(acc[t][0]); o.y = f2bf(acc[t][1]);
                o.z = f2bf(acc[t][2]); o.w = f2bf(acc[t][3]);
                *(ushort4*)&orow[t * 16 + quad * 4] = o;
            }
        }
    }
}

// ---------------------------------------------------------------------------
// Gather + GELU + residual + LayerNorm.
// One 64-lane wave per dst node: lane -> (b = lane>>5, chunk c4 = lane&31).
// M interleaved: logical (b, s) row at ushort4 index s*64 + b*32 + c4
//                = s*64 + lane  -> 512 contiguous bytes per wave per edge.
// ---------------------------------------------------------------------------
__global__ __launch_bounds__(256) void gather_kernel(
    const bf16_t* __restrict__ M, const float* __restrict__ Hmat,
    const int* __restrict__ cursor, const u16* __restrict__ eidxT,
    const float* __restrict__ gamma, const float* __restrict__ beta,
    float* __restrict__ out, int N)
{
    const int wave = threadIdx.x >> 6;
    const int lane = threadIdx.x & 63;
    const int node = blockIdx.x * 4 + wave;
    if (node >= N) return;

    const int b  = lane >> 5;
    const int c4 = lane & 31;

    int cnt = cursor[node];
    if (cnt > CAP) cnt = CAP;

    // lane l holds the index of edge slot l (transposed bucket read)
    int myidx = (lane < cnt) ? (int)eidxT[(size_t)lane * N + node] : 0;

    const ushort4* M4 = (const ushort4*)M;

    float acc0 = 0.f, acc1 = 0.f, acc2 = 0.f, acc3 = 0.f;
    int j = 0;
    for (; j + 8 <= cnt; j += 8) {
        ushort4 v[8];
        #pragma unroll
        for (int q = 0; q < 8; ++q) {
            int s = __shfl(myidx, j + q, 64);
            v[q] = M4[(size_t)s * 64 + lane];
        }
        #pragma unroll
        for (int q = 0; q < 8; ++q) {
            acc0 += bf2f(v[q].x); acc1 += bf2f(v[q].y);
            acc2 += bf2f(v[q].z); acc3 += bf2f(v[q].w);
        }
    }
    for (; j < cnt; ++j) {
        int s = __shfl(myidx, j, 64);
        ushort4 v0 = M4[(size_t)s * 64 + lane];
        acc0 += bf2f(v0.x); acc1 += bf2f(v0.y);
        acc2 += bf2f(v0.z); acc3 += bf2f(v0.w);
    }

    // x = H + gelu_exact(acc)
    const size_t elembase = ((size_t)b * N + node) * DIM + c4 * 4;
    float4 h = *(const float4*)&Hmat[elembase];
    const float inv_sqrt2 = 0.70710678118654752f;
    float x0 = h.x + 0.5f * acc0 * (1.f + erff(acc0 * inv_sqrt2));
    float x1 = h.y + 0.5f * acc1 * (1.f + erff(acc1 * inv_sqrt2));
    float x2 = h.z + 0.5f * acc2 * (1.f + erff(acc2 * inv_sqrt2));
    float x3 = h.w + 0.5f * acc3 * (1.f + erff(acc3 * inv_sqrt2));

    // LayerNorm over the 32-lane half-wave (128 elems)
    float s  = x0 + x1 + x2 + x3;
    float ss = x0 * x0 + x1 * x1 + x2 * x2 + x3 * x3;
    #pragma unroll
    for (int o = 16; o > 0; o >>= 1) {
        s  += __shfl_xor(s,  o, 64);
        ss += __shfl_xor(ss, o, 64);
    }
    const float mean = s * (1.f / DIM);
    const float var  = ss * (1.f / DIM) - mean * mean;
    const float inv  = rsqrtf(var + LN_EPS);

    float4 gm = *(const float4*)&gamma[c4 * 4];
    float4 bt = *(const float4*)&beta[c4 * 4];
    float4 o;
    o.x = (x0 - mean) * inv * gm.x + bt.x;
    o.y = (x1 - mean) * inv * gm.y + bt.y;
    o.z = (x2 - mean) * inv * gm.z + bt.z;
    o.w = (x3 - mean) * inv * gm.w + bt.w;
    *(float4*)&out[elembase] = o;
}

// ---------------------------------------------------------------------------
extern "C" void kernel_launch(void* const* d_in, const int* in_sizes, int n_in,
                              void* d_out, int out_size, void* d_ws, size_t ws_size,
                              hipStream_t stream)
{
    const float* H     = (const float*)d_in[0];
    const int*   src   = (const int*)  d_in[1];
    const int*   dst   = (const int*)  d_in[2];
    const float* W     = (const float*)d_in[3];
    const float* gamma = (const float*)d_in[4];
    const float* beta  = (const float*)d_in[5];
    float* out = (float*)d_out;

    const int E     = in_sizes[1];
    const int total = in_sizes[0];      // B * N * D
    const int nrows = total / DIM;      // B * N
    const int N     = nrows / 2;        // B = 2 per reference

    // Workspace layout (~32.3 MB)
    char* ws = (char*)d_ws;
    bf16_t* Mbuf = (bf16_t*)ws;   ws += (size_t)total * sizeof(bf16_t);
    int* cursor  = (int*)ws;      ws += (size_t)N * sizeof(int);
    u16* eidxT   = (u16*)ws;      ws += (size_t)CAP * N * sizeof(u16);
    bf16_t* WT   = (bf16_t*)ws;   ws += (size_t)DIM * DIM * sizeof(bf16_t);

    // 0) prep: cursor = 0 + WT = bf16(W^T)
    int prep_elems = (N > DIM * DIM / 4) ? N : DIM * DIM / 4;
    prep_kernel<<<(prep_elems + 255) / 256, 256, 0, stream>>>(W, WT, cursor, N);

    // 1) edge bucketing (high-occupancy, ~3 us)
    fill_kernel<<<(E + 255) / 256, 256, 0, stream>>>(src, dst, cursor, eidxT, N, E);

    // 2) m = H @ W: swapped-operand MFMA, W fragments resident in registers
    const int ROWS_PER_BLOCK = 4 * TPW * 16;   // 4 waves x TPW tiles x 16 rows
    gemm_kernel<<<(nrows + ROWS_PER_BLOCK - 1) / ROWS_PER_BLOCK, 256, 0, stream>>>(
        H, WT, Mbuf, nrows, N);

    // 3) fused gather + gelu + residual + layernorm
    gather_kernel<<<(N + 3) / 4, 256, 0, stream>>>(Mbuf, H, cursor, eidxT,
                                                   gamma, beta, out, N);
}

// Round 3
// 225.868 us; speedup vs baseline: 1.0315x; 1.0288x over previous
//
#include <hip/hip_runtime.h>
#include <math.h>

#define DIM 128
#define LN_EPS 1e-5f
#define CAP 64          // max in-degree capacity (Poisson(16): P(>64) ~ 1e-21)
#define TPW 2           // row-tiles (16 H-rows) per wave in gemm part

typedef unsigned short bf16_t;
typedef unsigned short u16;
typedef __attribute__((ext_vector_type(8))) short bf16x8;
typedef __attribute__((ext_vector_type(4))) float f32x4;

__device__ __forceinline__ bf16_t f2bf(float f) {
    unsigned u = __builtin_bit_cast(unsigned, f);
    u += 0x7FFFu + ((u >> 16) & 1u);          // round-to-nearest-even
    return (bf16_t)(u >> 16);
}
__device__ __forceinline__ float bf2f(bf16_t h) {
    unsigned u = ((unsigned)h) << 16;
    return __builtin_bit_cast(float, u);
}

// ---------------------------------------------------------------------------
// Prep: zero cursor (replaces memset) + build WT = bf16(W^T) once in global
// (32 KB). WT[n][k] rows are contiguous -> A-fragment loads are 16B vector.
// ---------------------------------------------------------------------------
__global__ __launch_bounds__(256) void prep_kernel(
    const float* __restrict__ W, bf16_t* __restrict__ WT,
    int* __restrict__ cursor, int N)
{
    const int tid = blockIdx.x * 256 + threadIdx.x;
    if (tid < N) cursor[tid] = 0;
    if (tid < (DIM * DIM / 4)) {
        const float4 w = ((const float4*)W)[tid];   // W[k][n0..n0+3], coalesced
        const int k  = tid >> 5;                    // 0..127
        const int n0 = (tid & 31) * 4;
        WT[(n0 + 0) * DIM + k] = f2bf(w.x);
        WT[(n0 + 1) * DIM + k] = f2bf(w.y);
        WT[(n0 + 2) * DIM + k] = f2bf(w.z);
        WT[(n0 + 3) * DIM + k] = f2bf(w.w);
    }
}

// ---------------------------------------------------------------------------
// FUSED kernel (round-0 structure restored for overlap): blocks [0, FB) do
// edge bucketing (4 edges/thread, int4 loads, 4 independent atomic chains);
// blocks [FB, FB+GB) do m = H @ W via swapped-operand MFMA:
//   A <- WT fragments: loop-invariant -> loaded ONCE per wave into 32 bf16x8
//        (128 VGPRs). __launch_bounds__(256, 2) caps at 2 waves/SIMD ->
//        256-VGPR budget so the W-file CANNOT spill (round-2 risk).
//   B <- H row fragments: lane reads its OWN row contiguously (2 x float4).
//   D: col(lane&15) = H-row, row(quad*4+r) = output dim -> each lane holds 4
//        consecutive output dims -> vectorized ushort4 epilogue stores.
// Fill is latency/atomic-bound, gemm is memory-bound: complementary pipes,
// so overlapping them (fill blocks dispatch first) hides the cheaper one.
// ---------------------------------------------------------------------------
__global__ __launch_bounds__(256, 2) void gemm_fill_kernel(
    const float* __restrict__ Hmat, const bf16_t* __restrict__ WT,
    bf16_t* __restrict__ Mout,
    const int* __restrict__ src, const int* __restrict__ dst,
    int* __restrict__ cursor, u16* __restrict__ eidxT,
    int nrows, int N, int E, int FB)
{
    if ((int)blockIdx.x < FB) {
        // ---- fill part: 4 edges per thread ----
        const int base = (blockIdx.x * 256 + threadIdx.x) * 4;
        if (base + 3 < E) {
            int4 d4 = *(const int4*)&dst[base];
            int4 s4 = *(const int4*)&src[base];
            int p0 = atomicAdd(&cursor[d4.x], 1);
            int p1 = atomicAdd(&cursor[d4.y], 1);
            int p2 = atomicAdd(&cursor[d4.z], 1);
            int p3 = atomicAdd(&cursor[d4.w], 1);
            if (p0 < CAP) eidxT[(size_t)p0 * N + d4.x] = (u16)s4.x;
            if (p1 < CAP) eidxT[(size_t)p1 * N + d4.y] = (u16)s4.y;
            if (p2 < CAP) eidxT[(size_t)p2 * N + d4.z] = (u16)s4.z;
            if (p3 < CAP) eidxT[(size_t)p3 * N + d4.w] = (u16)s4.w;
        } else {
            for (int e = base; e < E; ++e) {
                int d = dst[e];
                int pos = atomicAdd(&cursor[d], 1);
                if (pos < CAP) eidxT[(size_t)pos * N + d] = (u16)src[e];
            }
        }
        return;
    }

    // ---- gemm part ----
    const int tid  = threadIdx.x;
    const int wave = tid >> 6;
    const int lane = tid & 63;
    const int quad = lane >> 4;
    const int l15  = lane & 15;

    // Load all W fragments once: wf[t*4+ks] = A-frag of out-tile t, k-step ks
    bf16x8 wf[32];
    #pragma unroll
    for (int t = 0; t < 8; ++t)
        #pragma unroll
        for (int ks = 0; ks < 4; ++ks)
            wf[t * 4 + ks] = *(const bf16x8*)
                &WT[(size_t)(t * 16 + l15) * DIM + ks * 32 + quad * 8];

    const int gblock  = blockIdx.x - FB;
    const int baserow = (gblock * 4 + wave) * (TPW * 16);

    #pragma unroll
    for (int rt = 0; rt < TPW; ++rt) {
        const int arow = baserow + rt * 16 + l15;
        const float* Arow = Hmat + (size_t)((arow < nrows) ? arow : 0) * DIM;

        f32x4 acc[8];
        #pragma unroll
        for (int t = 0; t < 8; ++t) acc[t] = (f32x4){0.f, 0.f, 0.f, 0.f};

        #pragma unroll
        for (int ks = 0; ks < 4; ++ks) {
            const int k0 = ks * 32 + quad * 8;
            float4 a0 = *(const float4*)&Arow[k0];
            float4 a1 = *(const float4*)&Arow[k0 + 4];
            bf16x8 hf;
            hf[0] = (short)f2bf(a0.x); hf[1] = (short)f2bf(a0.y);
            hf[2] = (short)f2bf(a0.z); hf[3] = (short)f2bf(a0.w);
            hf[4] = (short)f2bf(a1.x); hf[5] = (short)f2bf(a1.y);
            hf[6] = (short)f2bf(a1.z); hf[7] = (short)f2bf(a1.w);

            #pragma unroll
            for (int t = 0; t < 8; ++t)
                acc[t] = __builtin_amdgcn_mfma_f32_16x16x32_bf16(
                             wf[t * 4 + ks], hf, acc[t], 0, 0, 0);
        }

        // Epilogue: lane holds M[arow][t*16 + quad*4 + r], r=0..3 consecutive.
        if (arow < nrows) {
            const int b = (arow >= N) ? 1 : 0;
            const int n = arow - (b ? N : 0);
            bf16_t* orow = Mout + ((size_t)n * 2 + b) * DIM;
            #pragma unroll
            for (int t = 0; t < 8; ++t) {
                ushort4 o;
                o.x = f2bf(acc[t][0]); o.y = f2bf(acc[t][1]);
                o.z = f2bf(acc[t][2]); o.w = f2bf(acc[t][3]);
                *(ushort4*)&orow[t * 16 + quad * 4] = o;
            }
        }
    }
}

// ---------------------------------------------------------------------------
// Gather + GELU + residual + LayerNorm.
// One 64-lane wave per dst node: lane -> (b = lane>>5, chunk c4 = lane&31).
// Edge-slot index broadcast uses __builtin_amdgcn_readlane (index j+q is
// wave-uniform): SGPR row index -> SCALAR address math -> saddr-form loads
// with fixed per-lane voffset. Removes ds_bpermute + per-lane 64-bit vector
// address math per edge (round-2's 52% VALUBusy).
// M interleaved: logical (b, s) row at ushort4 index s*64 + lane
//   -> 512 contiguous bytes per wave per edge.
// ---------------------------------------------------------------------------
__global__ __launch_bounds__(256) void gather_kernel(
    const bf16_t* __restrict__ M, const float* __restrict__ Hmat,
    const int* __restrict__ cursor, const u16* __restrict__ eidxT,
    const float* __restrict__ gamma, const float* __restrict__ beta,
    float* __restrict__ out, int N)
{
    const int wave = threadIdx.x >> 6;
    const int lane = threadIdx.x & 63;
    const int node = blockIdx.x * 4 + wave;
    if (node >= N) return;

    const int b  = lane >> 5;
    const int c4 = lane & 31;

    int cnt = cursor[node];
    if (cnt > CAP) cnt = CAP;

    // lane l holds the index of edge slot l (transposed bucket read)
    int myidx = (lane < cnt) ? (int)eidxT[(size_t)lane * N + node] : 0;

    const ushort4* M4 = (const ushort4*)M;

    float acc0 = 0.f, acc1 = 0.f, acc2 = 0.f, acc3 = 0.f;
    int j = 0;
    for (; j + 8 <= cnt; j += 8) {
        ushort4 v[8];
        #pragma unroll
        for (int q = 0; q < 8; ++q) {
            int s = __builtin_amdgcn_readlane(myidx, j + q);   // SGPR
            v[q] = (M4 + ((size_t)s << 6))[lane];              // saddr + lane*8
        }
        #pragma unroll
        for (int q = 0; q < 8; ++q) {
            acc0 += bf2f(v[q].x); acc1 += bf2f(v[q].y);
            acc2 += bf2f(v[q].z); acc3 += bf2f(v[q].w);
        }
    }
    for (; j < cnt; ++j) {
        int s = __builtin_amdgcn_readlane(myidx, j);
        ushort4 v0 = (M4 + ((size_t)s << 6))[lane];
        acc0 += bf2f(v0.x); acc1 += bf2f(v0.y);
        acc2 += bf2f(v0.z); acc3 += bf2f(v0.w);
    }

    // x = H + gelu_exact(acc)
    const size_t elembase = ((size_t)b * N + node) * DIM + c4 * 4;
    float4 h = *(const float4*)&Hmat[elembase];
    const float inv_sqrt2 = 0.70710678118654752f;
    float x0 = h.x + 0.5f * acc0 * (1.f + erff(acc0 * inv_sqrt2));
    float x1 = h.y + 0.5f * acc1 * (1.f + erff(acc1 * inv_sqrt2));
    float x2 = h.z + 0.5f * acc2 * (1.f + erff(acc2 * inv_sqrt2));
    float x3 = h.w + 0.5f * acc3 * (1.f + erff(acc3 * inv_sqrt2));

    // LayerNorm over the 32-lane half-wave (128 elems)
    float s  = x0 + x1 + x2 + x3;
    float ss = x0 * x0 + x1 * x1 + x2 * x2 + x3 * x3;
    #pragma unroll
    for (int o = 16; o > 0; o >>= 1) {
        s  += __shfl_xor(s,  o, 64);
        ss += __shfl_xor(ss, o, 64);
    }
    const float mean = s * (1.f / DIM);
    const float var  = ss * (1.f / DIM) - mean * mean;
    const float inv  = rsqrtf(var + LN_EPS);

    float4 gm = *(const float4*)&gamma[c4 * 4];
    float4 bt = *(const float4*)&beta[c4 * 4];
    float4 o;
    o.x = (x0 - mean) * inv * gm.x + bt.x;
    o.y = (x1 - mean) * inv * gm.y + bt.y;
    o.z = (x2 - mean) * inv * gm.z + bt.z;
    o.w = (x3 - mean) * inv * gm.w + bt.w;
    *(float4*)&out[elembase] = o;
}

// ---------------------------------------------------------------------------
extern "C" void kernel_launch(void* const* d_in, const int* in_sizes, int n_in,
                              void* d_out, int out_size, void* d_ws, size_t ws_size,
                              hipStream_t stream)
{
    const float* H     = (const float*)d_in[0];
    const int*   src   = (const int*)  d_in[1];
    const int*   dst   = (const int*)  d_in[2];
    const float* W     = (const float*)d_in[3];
    const float* gamma = (const float*)d_in[4];
    const float* beta  = (const float*)d_in[5];
    float* out = (float*)d_out;

    const int E     = in_sizes[1];
    const int total = in_sizes[0];      // B * N * D
    const int nrows = total / DIM;      // B * N
    const int N     = nrows / 2;        // B = 2 per reference

    // Workspace layout (~32.3 MB)
    char* ws = (char*)d_ws;
    bf16_t* Mbuf = (bf16_t*)ws;   ws += (size_t)total * sizeof(bf16_t);
    int* cursor  = (int*)ws;      ws += (size_t)N * sizeof(int);
    u16* eidxT   = (u16*)ws;      ws += (size_t)CAP * N * sizeof(u16);
    bf16_t* WT   = (bf16_t*)ws;   ws += (size_t)DIM * DIM * sizeof(bf16_t);

    // 0) prep: cursor = 0 + WT = bf16(W^T)
    int prep_elems = (N > DIM * DIM / 4) ? N : DIM * DIM / 4;
    prep_kernel<<<(prep_elems + 255) / 256, 256, 0, stream>>>(W, WT, cursor, N);

    // 1+2) fused: edge bucketing (4 edges/thread) || m = H @ W
    const int FB = (E + 1023) / 1024;                       // fill blocks (first)
    const int ROWS_PER_BLOCK = 4 * TPW * 16;                // 4 waves x TPW x 16
    const int GB = (nrows + ROWS_PER_BLOCK - 1) / ROWS_PER_BLOCK;
    gemm_fill_kernel<<<FB + GB, 256, 0, stream>>>(H, WT, Mbuf, src, dst,
                                                  cursor, eidxT, nrows, N, E, FB);

    // 3) fused gather + gelu + residual + layernorm
    gather_kernel<<<(N + 3) / 4, 256, 0, stream>>>(Mbuf, H, cursor, eidxT,
                                                   gamma, beta, out, N);
}

// Round 4
// 224.336 us; speedup vs baseline: 1.0386x; 1.0068x over previous
//
#include <hip/hip_runtime.h>
#include <math.h>

#define DIM 128
#define LN_EPS 1e-5f
#define RCAP 32         // per-replica slot capacity (2 replicas -> 64 slots total)
#define CSTRIDE 8       // cursor padding: 8 ints = 32B per counter (line-conflict fix)
#define TPW 2           // row-tiles (16 H-rows) per wave in gemm part

typedef unsigned short bf16_t;
typedef unsigned short u16;
typedef __attribute__((ext_vector_type(8))) short bf16x8;
typedef __attribute__((ext_vector_type(4))) float f32x4;

__device__ __forceinline__ bf16_t f2bf(float f) {
    unsigned u = __builtin_bit_cast(unsigned, f);
    u += 0x7FFFu + ((u >> 16) & 1u);          // round-to-nearest-even
    return (bf16_t)(u >> 16);
}
__device__ __forceinline__ float bf2f(bf16_t h) {
    unsigned u = ((unsigned)h) << 16;
    return __builtin_bit_cast(float, u);
}

// ---------------------------------------------------------------------------
// Prep: build WT = bf16(W^T) once in global (32 KB). Cursor zeroing moved to
// hipMemsetAsync (padded cursor is 3.2 MB).
// ---------------------------------------------------------------------------
__global__ __launch_bounds__(256) void prep_kernel(
    const float* __restrict__ W, bf16_t* __restrict__ WT)
{
    const int tid = blockIdx.x * 256 + threadIdx.x;
    if (tid < (DIM * DIM / 4)) {
        const float4 w = ((const float4*)W)[tid];   // W[k][n0..n0+3], coalesced
        const int k  = tid >> 5;                    // 0..127
        const int n0 = (tid & 31) * 4;
        WT[(n0 + 0) * DIM + k] = f2bf(w.x);
        WT[(n0 + 1) * DIM + k] = f2bf(w.y);
        WT[(n0 + 2) * DIM + k] = f2bf(w.z);
        WT[(n0 + 3) * DIM + k] = f2bf(w.w);
    }
}

// ---------------------------------------------------------------------------
// FUSED kernel: blocks [0, FB) = edge bucketing, blocks [FB, FB+GB) = gemm.
// FILL (the measured ~70us critical path, rounds 0/3 invariant):
//   - cursor padded to 32B/counter: kills 32-counters-per-line serialization
//   - 2 replicas selected by edge parity, slot ranges [0,32) and [32,64):
//     halves the same-address atomic chains (deg/2 per replica)
// GEMM part: byte-identical to round 3 (hidden under fill's critical path).
// ---------------------------------------------------------------------------
__global__ __launch_bounds__(256, 2) void gemm_fill_kernel(
    const float* __restrict__ Hmat, const bf16_t* __restrict__ WT,
    bf16_t* __restrict__ Mout,
    const int* __restrict__ src, const int* __restrict__ dst,
    int* __restrict__ cursor, u16* __restrict__ eidxT,
    int nrows, int N, int E, int FB)
{
    if ((int)blockIdx.x < FB) {
        // ---- fill part: 4 edges per thread, replica = edge parity ----
        const int base = (blockIdx.x * 256 + threadIdx.x) * 4;
        if (base + 3 < E) {
            int4 d4 = *(const int4*)&dst[base];
            int4 s4 = *(const int4*)&src[base];
            int p0 = atomicAdd(&cursor[((size_t)0 + d4.x) * CSTRIDE], 1);
            int p1 = atomicAdd(&cursor[((size_t)N + d4.y) * CSTRIDE], 1);
            int p2 = atomicAdd(&cursor[((size_t)0 + d4.z) * CSTRIDE], 1);
            int p3 = atomicAdd(&cursor[((size_t)N + d4.w) * CSTRIDE], 1);
            if (p0 < RCAP) eidxT[(size_t)(p0)        * N + d4.x] = (u16)s4.x;
            if (p1 < RCAP) eidxT[(size_t)(RCAP + p1) * N + d4.y] = (u16)s4.y;
            if (p2 < RCAP) eidxT[(size_t)(p2)        * N + d4.z] = (u16)s4.z;
            if (p3 < RCAP) eidxT[(size_t)(RCAP + p3) * N + d4.w] = (u16)s4.w;
        } else {
            for (int e = base; e < E; ++e) {
                int d = dst[e];
                int r = e & 1;
                int pos = atomicAdd(&cursor[((size_t)r * N + d) * CSTRIDE], 1);
                if (pos < RCAP)
                    eidxT[(size_t)(r * RCAP + pos) * N + d] = (u16)src[e];
            }
        }
        return;
    }

    // ---- gemm part (identical to round 3) ----
    const int tid  = threadIdx.x;
    const int wave = tid >> 6;
    const int lane = tid & 63;
    const int quad = lane >> 4;
    const int l15  = lane & 15;

    bf16x8 wf[32];
    #pragma unroll
    for (int t = 0; t < 8; ++t)
        #pragma unroll
        for (int ks = 0; ks < 4; ++ks)
            wf[t * 4 + ks] = *(const bf16x8*)
                &WT[(size_t)(t * 16 + l15) * DIM + ks * 32 + quad * 8];

    const int gblock  = blockIdx.x - FB;
    const int baserow = (gblock * 4 + wave) * (TPW * 16);

    #pragma unroll
    for (int rt = 0; rt < TPW; ++rt) {
        const int arow = baserow + rt * 16 + l15;
        const float* Arow = Hmat + (size_t)((arow < nrows) ? arow : 0) * DIM;

        f32x4 acc[8];
        #pragma unroll
        for (int t = 0; t < 8; ++t) acc[t] = (f32x4){0.f, 0.f, 0.f, 0.f};

        #pragma unroll
        for (int ks = 0; ks < 4; ++ks) {
            const int k0 = ks * 32 + quad * 8;
            float4 a0 = *(const float4*)&Arow[k0];
            float4 a1 = *(const float4*)&Arow[k0 + 4];
            bf16x8 hf;
            hf[0] = (short)f2bf(a0.x); hf[1] = (short)f2bf(a0.y);
            hf[2] = (short)f2bf(a0.z); hf[3] = (short)f2bf(a0.w);
            hf[4] = (short)f2bf(a1.x); hf[5] = (short)f2bf(a1.y);
            hf[6] = (short)f2bf(a1.z); hf[7] = (short)f2bf(a1.w);

            #pragma unroll
            for (int t = 0; t < 8; ++t)
                acc[t] = __builtin_amdgcn_mfma_f32_16x16x32_bf16(
                             wf[t * 4 + ks], hf, acc[t], 0, 0, 0);
        }

        if (arow < nrows) {
            const int b = (arow >= N) ? 1 : 0;
            const int n = arow - (b ? N : 0);
            bf16_t* orow = Mout + ((size_t)n * 2 + b) * DIM;
            #pragma unroll
            for (int t = 0; t < 8; ++t) {
                ushort4 o;
                o.x = f2bf(acc[t][0]); o.y = f2bf(acc[t][1]);
                o.z = f2bf(acc[t][2]); o.w = f2bf(acc[t][3]);
                *(ushort4*)&orow[t * 16 + quad * 4] = o;
            }
        }
    }
}

// ---------------------------------------------------------------------------
// Gather + GELU + residual + LayerNorm.
// One 64-lane wave per dst node: lane l holds edge-slot l's src index.
// Two replica slot ranges: [0, c0) and [32, 32+c1).
// Batched-tail: every 8-slot batch issues all 8 loads unconditionally
// (invalid slots read row 0 via myidx=0 — in-bounds, discarded by a
// wave-uniform guard) -> tail edges also get 8-deep MLP.
// ---------------------------------------------------------------------------
__global__ __launch_bounds__(256) void gather_kernel(
    const bf16_t* __restrict__ M, const float* __restrict__ Hmat,
    const int* __restrict__ cursor, const u16* __restrict__ eidxT,
    const float* __restrict__ gamma, const float* __restrict__ beta,
    float* __restrict__ out, int N)
{
    const int wave = threadIdx.x >> 6;
    const int lane = threadIdx.x & 63;
    const int node = blockIdx.x * 4 + wave;
    if (node >= N) return;

    const int b  = lane >> 5;
    const int c4 = lane & 31;

    int c0 = cursor[(size_t)node * CSTRIDE];
    int c1 = cursor[((size_t)N + node) * CSTRIDE];
    if (c0 > RCAP) c0 = RCAP;
    if (c1 > RCAP) c1 = RCAP;

    // lane l holds slot l's src index (0 if slot invalid -> row 0, discarded)
    const bool valid = (lane < RCAP) ? (lane < c0) : ((lane - RCAP) < c1);
    int myidx = valid ? (int)eidxT[(size_t)lane * N + node] : 0;

    const ushort4* M4 = (const ushort4*)M;

    float acc0 = 0.f, acc1 = 0.f, acc2 = 0.f, acc3 = 0.f;
    #pragma unroll
    for (int half = 0; half < 2; ++half) {
        const int j0  = half * RCAP;
        const int cnt = half ? c1 : c0;
        for (int j = 0; j < cnt; j += 8) {
            ushort4 v[8];
            #pragma unroll
            for (int q = 0; q < 8; ++q) {
                int s = __builtin_amdgcn_readlane(myidx, j0 + j + q);  // SGPR
                v[q] = (M4 + ((size_t)s << 6))[lane];                  // saddr
            }
            #pragma unroll
            for (int q = 0; q < 8; ++q) {
                if (j + q < cnt) {                                     // uniform
                    acc0 += bf2f(v[q].x); acc1 += bf2f(v[q].y);
                    acc2 += bf2f(v[q].z); acc3 += bf2f(v[q].w);
                }
            }
        }
    }

    // x = H + gelu_exact(acc)
    const size_t elembase = ((size_t)b * N + node) * DIM + c4 * 4;
    float4 h = *(const float4*)&Hmat[elembase];
    const float inv_sqrt2 = 0.70710678118654752f;
    float x0 = h.x + 0.5f * acc0 * (1.f + erff(acc0 * inv_sqrt2));
    float x1 = h.y + 0.5f * acc1 * (1.f + erff(acc1 * inv_sqrt2));
    float x2 = h.z + 0.5f * acc2 * (1.f + erff(acc2 * inv_sqrt2));
    float x3 = h.w + 0.5f * acc3 * (1.f + erff(acc3 * inv_sqrt2));

    // LayerNorm over the 32-lane half-wave (128 elems)
    float s  = x0 + x1 + x2 + x3;
    float ss = x0 * x0 + x1 * x1 + x2 * x2 + x3 * x3;
    #pragma unroll
    for (int o = 16; o > 0; o >>= 1) {
        s  += __shfl_xor(s,  o, 64);
        ss += __shfl_xor(ss, o, 64);
    }
    const float mean = s * (1.f / DIM);
    const float var  = ss * (1.f / DIM) - mean * mean;
    const float inv  = rsqrtf(var + LN_EPS);

    float4 gm = *(const float4*)&gamma[c4 * 4];
    float4 bt = *(const float4*)&beta[c4 * 4];
    float4 o;
    o.x = (x0 - mean) * inv * gm.x + bt.x;
    o.y = (x1 - mean) * inv * gm.y + bt.y;
    o.z = (x2 - mean) * inv * gm.z + bt.z;
    o.w = (x3 - mean) * inv * gm.w + bt.w;
    *(float4*)&out[elembase] = o;
}

// ---------------------------------------------------------------------------
extern "C" void kernel_launch(void* const* d_in, const int* in_sizes, int n_in,
                              void* d_out, int out_size, void* d_ws, size_t ws_size,
                              hipStream_t stream)
{
    const float* H     = (const float*)d_in[0];
    const int*   src   = (const int*)  d_in[1];
    const int*   dst   = (const int*)  d_in[2];
    const float* W     = (const float*)d_in[3];
    const float* gamma = (const float*)d_in[4];
    const float* beta  = (const float*)d_in[5];
    float* out = (float*)d_out;

    const int E     = in_sizes[1];
    const int total = in_sizes[0];      // B * N * D
    const int nrows = total / DIM;      // B * N
    const int N     = nrows / 2;        // B = 2 per reference

    // Workspace layout (~35.5 MB)
    char* ws = (char*)d_ws;
    bf16_t* Mbuf = (bf16_t*)ws;   ws += (size_t)total * sizeof(bf16_t);           // 25.6 MB
    int* cursor  = (int*)ws;      ws += (size_t)2 * N * CSTRIDE * sizeof(int);    //  3.2 MB
    u16* eidxT   = (u16*)ws;      ws += (size_t)2 * RCAP * N * sizeof(u16);       //  6.4 MB
    bf16_t* WT   = (bf16_t*)ws;   ws += (size_t)DIM * DIM * sizeof(bf16_t);       // 32 KB

    hipMemsetAsync(cursor, 0, (size_t)2 * N * CSTRIDE * sizeof(int), stream);

    // 0) prep: WT = bf16(W^T)
    prep_kernel<<<(DIM * DIM / 4 + 255) / 256, 256, 0, stream>>>(W, WT);

    // 1+2) fused: edge bucketing (padded+replicated cursor) || m = H @ W
    const int FB = (E + 1023) / 1024;                       // fill blocks (first)
    const int ROWS_PER_BLOCK = 4 * TPW * 16;                // 4 waves x TPW x 16
    const int GB = (nrows + ROWS_PER_BLOCK - 1) / ROWS_PER_BLOCK;
    gemm_fill_kernel<<<FB + GB, 256, 0, stream>>>(H, WT, Mbuf, src, dst,
                                                  cursor, eidxT, nrows, N, E, FB);

    // 3) fused gather + gelu + residual + layernorm
    gather_kernel<<<(N + 3) / 4, 256, 0, stream>>>(Mbuf, H, cursor, eidxT,
                                                   gamma, beta, out, N);
}